// Round 2
// baseline (4953.674 us; speedup 1.0000x reference)
//
#include <hip/hip_runtime.h>

typedef unsigned short u16;
typedef __attribute__((ext_vector_type(8))) short short8;   // 8 bf16 = 4 VGPRs (MFMA A/B frag)
typedef __attribute__((ext_vector_type(4))) float f32x4;    // MFMA C/D frag

#define N 1024
#define NSQ (1024 * 1024)
#define NITER 30

__device__ __forceinline__ float b2f(u16 u) {
  union { unsigned int i; float f; } v;
  v.i = ((unsigned int)u) << 16;
  return v.f;
}

__device__ __forceinline__ u16 f2b(float f) {
  union { float f; unsigned int i; } v;
  v.f = f;
  return (u16)((v.i + 0x7fffu + ((v.i >> 16) & 1u)) >> 16);
}

// ---- input dtype detection -------------------------------------------------
__global__ void k_flag(const u16* a, float* flag) {
  if (threadIdx.x == 0 && blockIdx.x == 0) {
    int cnt = 0;
    for (int i = 0; i < 256; ++i) {
      const u16 u = a[2 * i];
      const int e = (u >> 7) & 0xFF;
      if (e >= 100 && e <= 132) ++cnt;
    }
    *flag = (cnt >= 128) ? 1.0f : 0.0f;
  }
}

__global__ void k_sentinel(void* out, const float* flag) {
  if (threadIdx.x == 0 && blockIdx.x == 0) {
    if (*flag > 0.5f) ((u16*)out)[0] = f2b(1000.0f);
    else              ((float*)out)[0] = 1000.0f;
  }
}

__global__ void k_cvt2(const void* a, float* o, const float* flag, int n) {
  const int i = blockIdx.x * 256 + threadIdx.x;
  if (i < n) {
    if (*flag > 0.5f) o[i] = b2f(((const u16*)a)[i]);
    else              o[i] = ((const float*)a)[i];
  }
}

// ---- fp32 -> bf16 (hi, lo) split helpers -----------------------------------
__global__ void k_split(const float* x, u16* h, u16* l) {
  const int i = blockIdx.x * 256 + threadIdx.x;
  const float v = x[i];
  const u16 hi = f2b(v);
  h[i] = hi;
  l[i] = f2b(v - b2f(hi));
}

// T = A^T, split to bf16 hi/lo.  grid (32,32), block (32,8)
__global__ void k_tsplit(const float* A, u16* Th, u16* Tl) {
  __shared__ float s[32][33];
  const int bx = blockIdx.x, by = blockIdx.y;
  const int tx = threadIdx.x, ty = threadIdx.y;
  for (int p = 0; p < 4; ++p)
    s[ty + p * 8][tx] = A[(by * 32 + ty + p * 8) * N + bx * 32 + tx];
  __syncthreads();
  for (int p = 0; p < 4; ++p) {
    const int rT = bx * 32 + ty + p * 8;
    const int cT = by * 32 + tx;
    const float v = s[tx][ty + p * 8];   // = A[cT][rT]
    const u16 hi = f2b(v);
    Th[rT * N + cT] = hi;
    Tl[rT * N + cT] = f2b(v - b2f(hi));
  }
}

__global__ void k_fillsplit(u16* h, u16* l, float v) {
  const int i = blockIdx.x * 256 + threadIdx.x;
  const u16 hi = f2b(v);
  h[i] = hi;
  l[i] = f2b(v - b2f(hi));
}

// ---- split-fp32 NT GEMM via bf16 MFMA --------------------------------------
// C[m][n] = sum_p sum_k P_p[m][k] * Q_p[n][k]   (C = sum_p P_p * Q_p^T)
// hi*hi + hi*lo + lo*hi with fp32 MFMA accumulation (~2^-17 rel error).
struct NTJob {
  const u16* ph[2]; const u16* pl[2];
  const u16* qh[2]; const u16* ql[2];
  float* c; u16* ch; u16* cl;
  int npairs; int wantc; int wantsplit;
};
struct NTBatch { NTJob j[4]; };

#define GLDS(g, l) __builtin_amdgcn_global_load_lds(                         \
    (const __attribute__((address_space(1))) void*)(g),                      \
    (__attribute__((address_space(3))) void*)(l), 16, 0, 0)

// 64x64 tile, BK=32, 4 waves as 2x2 (per-wave 32x32), double-buffered LDS.
// Sized for occupancy: 32 KB LDS -> 5 blocks/CU cap; stage-1 grid (16,16,4)
// puts 4 blocks/CU (16 waves) vs the previous 1 block/CU that left every
// K-step's HBM latency exposed. Loads for step s+1 are issued right after
// the top barrier, so the barrier's implicit vmcnt(0) drain lands after a
// full step of MFMA work (single-level software pipeline).
// LDS [row][k] in 16B chunks with XOR swizzle (chunk ^= (row>>1)&3), applied
// on BOTH the pre-swizzled global source (linear global_load_lds dest) and
// the ds_read_b128 index -> 0 bank conflicts (verified last round).
__global__ __launch_bounds__(256) void k_nt(NTBatch batch) {
  __shared__ u16 Ah[2][64][32];
  __shared__ u16 Al[2][64][32];
  __shared__ u16 Bh[2][64][32];
  __shared__ u16 Bl[2][64][32];

  const NTJob job = batch.j[blockIdx.z];
  const int tid = threadIdx.x;
  const int w = tid >> 6, lane = tid & 63;
  const int m0 = blockIdx.y * 64, n0 = blockIdx.x * 64;

  // staging: wave w loads rows [w*16, w*16+16) of the 64-row panel
  const int srow = lane >> 2;             // 0..15
  const int sch  = lane & 3;              // dest 16B chunk within 64B row
  const int grow = w * 16 + srow;
  const long swz  = (long)((sch ^ ((grow >> 1) & 3)) << 4);
  const long aoff = (long)(m0 + grow) * (N * 2) + swz;
  const long boff = (long)(n0 + grow) * (N * 2) + swz;

  // fragment read indices (u16 units within one 64x32 buffer)
  const int r0 = lane & 15, g = lane >> 4;
  const int wm = (w & 1) * 32, wn = (w >> 1) * 32;
  int idxA[2], idxB[2];
#pragma unroll
  for (int mt = 0; mt < 2; ++mt) {
    const int row = wm + mt * 16 + r0;
    idxA[mt] = row * 32 + ((g ^ ((row >> 1) & 3)) << 3);
  }
#pragma unroll
  for (int nt = 0; nt < 2; ++nt) {
    const int row = wn + nt * 16 + r0;
    idxB[nt] = row * 32 + ((g ^ ((row >> 1) & 3)) << 3);
  }

  f32x4 acc[2][2];
#pragma unroll
  for (int mt = 0; mt < 2; ++mt)
#pragma unroll
    for (int nt = 0; nt < 2; ++nt)
      acc[mt][nt] = (f32x4){0.0f, 0.0f, 0.0f, 0.0f};

  auto issue = [&](int s, int p) {
    const int pair = s >> 5;
    const long kb = (long)(s & 31) * 64;
    GLDS((const char*)job.ph[pair] + aoff + kb, &Ah[p][w * 16][0]);
    GLDS((const char*)job.pl[pair] + aoff + kb, &Al[p][w * 16][0]);
    GLDS((const char*)job.qh[pair] + boff + kb, &Bh[p][w * 16][0]);
    GLDS((const char*)job.ql[pair] + boff + kb, &Bl[p][w * 16][0]);
  };

  const int nsteps = job.npairs * 32;
  issue(0, 0);
  for (int s = 0; s < nsteps; ++s) {
    const int p = s & 1;
    __syncthreads();   // drains vmcnt: buf p ready; all waves done reading p^1
    if (s + 1 < nsteps) issue(s + 1, p ^ 1);   // in flight during this step
    const u16* Ahf = &Ah[p][0][0];
    const u16* Alf = &Al[p][0][0];
    const u16* Bhf = &Bh[p][0][0];
    const u16* Blf = &Bl[p][0][0];
    short8 ah[2], al[2];
#pragma unroll
    for (int mt = 0; mt < 2; ++mt) {
      ah[mt] = *(const short8*)(Ahf + idxA[mt]);
      al[mt] = *(const short8*)(Alf + idxA[mt]);
    }
#pragma unroll
    for (int nt = 0; nt < 2; ++nt) {
      const short8 bh = *(const short8*)(Bhf + idxB[nt]);
      const short8 bl = *(const short8*)(Blf + idxB[nt]);
#pragma unroll
      for (int mt = 0; mt < 2; ++mt) {
        acc[mt][nt] = __builtin_amdgcn_mfma_f32_16x16x32_bf16(ah[mt], bh, acc[mt][nt], 0, 0, 0);
        acc[mt][nt] = __builtin_amdgcn_mfma_f32_16x16x32_bf16(ah[mt], bl, acc[mt][nt], 0, 0, 0);
        acc[mt][nt] = __builtin_amdgcn_mfma_f32_16x16x32_bf16(al[mt], bh, acc[mt][nt], 0, 0, 0);
      }
    }
  }

  // C/D layout (m89-verified): col = lane&15, row = (lane>>4)*4 + reg
#pragma unroll
  for (int mt = 0; mt < 2; ++mt) {
    const int crow = m0 + wm + mt * 16 + g * 4;
#pragma unroll
    for (int nt = 0; nt < 2; ++nt) {
      const int ccol = n0 + wn + nt * 16 + r0;
#pragma unroll
      for (int jj = 0; jj < 4; ++jj) {
        const float v = acc[mt][nt][jj];
        const int o = (crow + jj) * N + ccol;
        if (job.wantc) job.c[o] = v;
        if (job.wantsplit) {
          const u16 hi = f2b(v);
          job.ch[o] = hi;
          job.cl[o] = f2b(v - b2f(hi));
        }
      }
    }
  }
}

// ---- reductions -------------------------------------------------------------
__global__ void k_rsum(const float* x, float* slot) {
  __shared__ float red[256];
  const int tid = threadIdx.x;
  float a = 0.0f;
  for (int i = blockIdx.x * 256 + tid; i < NSQ; i += gridDim.x * 256)
    a += x[i] * x[i];
  red[tid] = a;
  __syncthreads();
  for (int off = 128; off > 0; off >>= 1) {
    if (tid < off) red[tid] += red[tid + off];
    __syncthreads();
  }
  if (tid == 0) atomicAdd(slot, red[0]);
}

__global__ void k_dot(const float* x, const float* y, float* slot) {
  __shared__ float red[256];
  const int tid = threadIdx.x;
  float a = 0.0f;
  for (int i = blockIdx.x * 256 + tid; i < NSQ; i += gridDim.x * 256)
    a += x[i] * y[i];
  red[tid] = a;
  __syncthreads();
  for (int off = 128; off > 0; off >>= 1) {
    if (tid < off) red[tid] += red[tid + off];
    __syncthreads();
  }
  if (tid == 0) atomicAdd(slot, red[0]);
}

// all 16 <U_ab, L_cd> dots in one pass (reads 8 arrays once, not 16 pairs)
__global__ void k_dot16(const float* U0, const float* U1, const float* U2, const float* U3,
                        const float* L0, const float* L1, const float* L2, const float* L3,
                        float* slots) {
  __shared__ float red[256];
  const int tid = threadIdx.x;
  float a[16];
#pragma unroll
  for (int u = 0; u < 16; ++u) a[u] = 0.0f;
  for (int i = blockIdx.x * 256 + tid; i < NSQ; i += gridDim.x * 256) {
    const float u0 = U0[i], u1 = U1[i], u2 = U2[i], u3 = U3[i];
    const float l0 = L0[i], l1 = L1[i], l2 = L2[i], l3 = L3[i];
    a[0]  += u0 * l0; a[1]  += u0 * l1; a[2]  += u0 * l2; a[3]  += u0 * l3;
    a[4]  += u1 * l0; a[5]  += u1 * l1; a[6]  += u1 * l2; a[7]  += u1 * l3;
    a[8]  += u2 * l0; a[9]  += u2 * l1; a[10] += u2 * l2; a[11] += u2 * l3;
    a[12] += u3 * l0; a[13] += u3 * l1; a[14] += u3 * l2; a[15] += u3 * l3;
  }
  for (int u = 0; u < 16; ++u) {
    red[tid] = a[u];
    __syncthreads();
    for (int off = 128; off > 0; off >>= 1) {
      if (tid < off) red[tid] += red[tid + off];
      __syncthreads();
    }
    if (tid == 0) atomicAdd(slots + 402 + u, red[0]);
    __syncthreads();
  }
}

__global__ void k_zero(float* p) {
  const int i = blockIdx.x * 256 + threadIdx.x;
  p[i] = 0.0f;
}

// Finalize. Unnormalized iterates: eig = <r,Tr>/<r,r>, E0 = sum h*dots/(lr*eig^2).
__global__ void GMPOmodel_6794638262737_kernel(const void* h, const float* slots,
                                               void* out) {
  if (threadIdx.x == 0 && blockIdx.x == 0) {
    const float bf = slots[512];
    const float rr = slots[399];
    const float rw = slots[400];
    const float lr = slots[401];
    const float eig = rw / rr;
    float num = 0.0f;
    for (int u = 0; u < 16; ++u) {
      const float hv = (bf > 0.5f) ? b2f(((const u16*)h)[u]) : ((const float*)h)[u];
      num += hv * slots[402 + u];
    }
    const float e0 = num / (lr * eig * eig);
    if (bf > 0.5f) ((u16*)out)[0] = f2b(e0);
    else           ((float*)out)[0] = e0;
  }
}

// ---- host -------------------------------------------------------------------
static inline NTJob mkjob(const u16* ph0, const u16* pl0, const u16* qh0, const u16* ql0,
                          const u16* ph1, const u16* pl1, const u16* qh1, const u16* ql1,
                          float* c, u16* ch, u16* cl, int npairs, int wantc, int wantsplit) {
  NTJob j;
  j.ph[0] = ph0; j.pl[0] = pl0; j.qh[0] = qh0; j.ql[0] = ql0;
  j.ph[1] = ph1; j.pl[1] = pl1; j.qh[1] = qh1; j.ql[1] = ql1;
  j.c = c; j.ch = ch; j.cl = cl;
  j.npairs = npairs; j.wantc = wantc; j.wantsplit = wantsplit;
  return j;
}

extern "C" void kernel_launch(void* const* d_in, const int* in_sizes, int n_in,
                              void* d_out, int out_size, void* d_ws, size_t ws_size,
                              hipStream_t stream) {
  (void)in_sizes; (void)n_in; (void)out_size; (void)ws_size;
  const void* Ain = d_in[0];
  const void* hin = d_in[1];
  char* ws = (char*)d_ws;
  const size_t MB = 1u << 20;

  // bf16 split buffers (2 MB each)
  u16* A0h = (u16*)(ws + 0 * MB);   u16* A0l = (u16*)(ws + 2 * MB);
  u16* A1h = (u16*)(ws + 4 * MB);   u16* A1l = (u16*)(ws + 6 * MB);
  u16* T0h = (u16*)(ws + 8 * MB);   u16* T0l = (u16*)(ws + 10 * MB);
  u16* T1h = (u16*)(ws + 12 * MB);  u16* T1l = (u16*)(ws + 14 * MB);
  u16* rh  = (u16*)(ws + 16 * MB);  u16* rl  = (u16*)(ws + 18 * MB);
  u16* lh  = (u16*)(ws + 20 * MB);  u16* ll  = (u16*)(ws + 22 * MB);
  u16* t0rh = (u16*)(ws + 24 * MB); u16* t0rl = (u16*)(ws + 26 * MB);
  u16* t1rh = (u16*)(ws + 28 * MB); u16* t1rl = (u16*)(ws + 30 * MB);
  u16* t0lh = (u16*)(ws + 32 * MB); u16* t0ll = (u16*)(ws + 34 * MB);
  u16* t1lh = (u16*)(ws + 36 * MB); u16* t1ll = (u16*)(ws + 38 * MB);
  // fp32 buffers (4 MB each); A0f/A1f reused as L00/L01, wf as U00
  float* A0f = (float*)(ws + 40 * MB);
  float* A1f = (float*)(ws + 44 * MB);
  float* rf  = (float*)(ws + 48 * MB);
  float* lf  = (float*)(ws + 52 * MB);
  float* wf  = (float*)(ws + 56 * MB);
  float* L10 = (float*)(ws + 60 * MB);
  float* L11 = (float*)(ws + 64 * MB);
  float* U01 = (float*)(ws + 68 * MB);
  float* U10 = (float*)(ws + 72 * MB);
  float* U11 = (float*)(ws + 76 * MB);
  float* slots = (float*)(ws + 80 * MB); // 1024 floats; [512] = dtype flag

  k_zero<<<4, 256, 0, stream>>>(slots);
  k_flag<<<1, 64, 0, stream>>>((const u16*)Ain, slots + 512);
  k_sentinel<<<1, 64, 0, stream>>>(d_out, slots + 512);
  k_cvt2<<<8192, 256, 0, stream>>>(Ain, A0f, slots + 512, 2 * NSQ);  // fills A0f, A1f

  k_split<<<4096, 256, 0, stream>>>(A0f, A0h, A0l);
  k_split<<<4096, 256, 0, stream>>>(A1f, A1h, A1l);
  k_tsplit<<<dim3(32, 32), dim3(32, 8), 0, stream>>>(A0f, T0h, T0l);
  k_tsplit<<<dim3(32, 32), dim3(32, 8), 0, stream>>>(A1f, T1h, T1l);
  k_fillsplit<<<4096, 256, 0, stream>>>(rh, rl, 1.0f / 1024.0f);
  k_fillsplit<<<4096, 256, 0, stream>>>(lh, ll, 1.0f / 1024.0f);

  // r, l stay symmetric (v0 symmetric, map preserves symmetry) -> all NT form.
  // Stage 1 (z=4): t0r=A0*r, t1r=A1*r, t0l=A0^T*l, t1l=A1^T*l
  NTBatch s1;
  s1.j[0] = mkjob(A0h, A0l, rh, rl, 0, 0, 0, 0, 0, t0rh, t0rl, 1, 0, 1);
  s1.j[1] = mkjob(A1h, A1l, rh, rl, 0, 0, 0, 0, 0, t1rh, t1rl, 1, 0, 1);
  s1.j[2] = mkjob(T0h, T0l, lh, ll, 0, 0, 0, 0, 0, t0lh, t0ll, 1, 0, 1);
  s1.j[3] = mkjob(T1h, T1l, lh, ll, 0, 0, 0, 0, 0, t1lh, t1ll, 1, 0, 1);
  // Stage 2 (z=2, dual-pair): r' = t0r*A0^T + t1r*A1^T ; l' = t0l*A0 + t1l*A1
  NTBatch s2;
  s2.j[0] = mkjob(t0rh, t0rl, A0h, A0l, t1rh, t1rl, A1h, A1l, rf, rh, rl, 2, 1, 1);
  s2.j[1] = mkjob(t0lh, t0ll, T0h, T0l, t1lh, t1ll, T1h, T1l, lf, lh, ll, 2, 1, 1);

  for (int it = 0; it < NITER; ++it) {
    k_nt<<<dim3(16, 16, 4), 256, 0, stream>>>(s1);
    k_nt<<<dim3(16, 16, 2), 256, 0, stream>>>(s2);
  }

  // ---- epilogue (unnormalized; E0 homogeneous deg 0 in r and l) ----
  NTBatch e1;
  e1.j[0] = mkjob(A0h, A0l, rh, rl, 0, 0, 0, 0, 0, t0rh, t0rl, 1, 0, 1);
  e1.j[1] = mkjob(A1h, A1l, rh, rl, 0, 0, 0, 0, 0, t1rh, t1rl, 1, 0, 1);
  k_nt<<<dim3(16, 16, 2), 256, 0, stream>>>(e1);
  NTBatch e2;
  e2.j[0] = mkjob(t0rh, t0rl, A0h, A0l, t1rh, t1rl, A1h, A1l, wf, 0, 0, 2, 1, 0);
  k_nt<<<dim3(16, 16, 1), 256, 0, stream>>>(e2);
  k_rsum<<<256, 256, 0, stream>>>(rf, slots + 399);          // rr
  k_dot<<<256, 256, 0, stream>>>(rf, wf, slots + 400);       // rw
  k_dot<<<256, 256, 0, stream>>>(lf, rf, slots + 401);       // lr

  // UL_a = l*A_a = NT(l, ATa); URT_b = (A_b r)^T = r*A_b^T = NT(r, A_b)
  NTBatch e3;
  e3.j[0] = mkjob(lh, ll, T0h, T0l, 0, 0, 0, 0, 0, t0lh, t0ll, 1, 0, 1);  // UL0
  e3.j[1] = mkjob(lh, ll, T1h, T1l, 0, 0, 0, 0, 0, t1lh, t1ll, 1, 0, 1);  // UL1
  e3.j[2] = mkjob(rh, rl, A0h, A0l, 0, 0, 0, 0, 0, t0rh, t0rl, 1, 0, 1);  // URT0
  e3.j[3] = mkjob(rh, rl, A1h, A1l, 0, 0, 0, 0, 0, t1rh, t1rl, 1, 0, 1);  // URT1
  k_nt<<<dim3(16, 16, 4), 256, 0, stream>>>(e3);

  // L_cd = A_c*A_d = NT(A_c, ATd); fp32 only.
  NTBatch e4;
  e4.j[0] = mkjob(A0h, A0l, T0h, T0l, 0, 0, 0, 0, A0f, 0, 0, 1, 1, 0);
  e4.j[1] = mkjob(A0h, A0l, T1h, T1l, 0, 0, 0, 0, A1f, 0, 0, 1, 1, 0);
  e4.j[2] = mkjob(A1h, A1l, T0h, T0l, 0, 0, 0, 0, L10, 0, 0, 1, 1, 0);
  e4.j[3] = mkjob(A1h, A1l, T1h, T1l, 0, 0, 0, 0, L11, 0, 0, 1, 1, 0);
  k_nt<<<dim3(16, 16, 4), 256, 0, stream>>>(e4);

  // U_ab = UL_a * UR_b = NT(UL_a, URT_b); wf dead after rw dot -> U00.
  NTBatch e5;
  e5.j[0] = mkjob(t0lh, t0ll, t0rh, t0rl, 0, 0, 0, 0, wf,  0, 0, 1, 1, 0);
  e5.j[1] = mkjob(t0lh, t0ll, t1rh, t1rl, 0, 0, 0, 0, U01, 0, 0, 1, 1, 0);
  e5.j[2] = mkjob(t1lh, t1ll, t0rh, t0rl, 0, 0, 0, 0, U10, 0, 0, 1, 1, 0);
  e5.j[3] = mkjob(t1lh, t1ll, t1rh, t1rl, 0, 0, 0, 0, U11, 0, 0, 1, 1, 0);
  k_nt<<<dim3(16, 16, 4), 256, 0, stream>>>(e5);

  k_dot16<<<256, 256, 0, stream>>>(wf, U01, U10, U11, A0f, A1f, L10, L11, slots);

  GMPOmodel_6794638262737_kernel<<<1, 64, 0, stream>>>(hin, slots, d_out);
}

// Round 4
// 2317.071 us; speedup vs baseline: 2.1379x; 2.1379x over previous
//
#include <hip/hip_runtime.h>

typedef unsigned short u16;
typedef __attribute__((ext_vector_type(8))) short short8;   // 8 bf16 = 4 VGPRs (MFMA A/B frag)
typedef __attribute__((ext_vector_type(4))) float f32x4;    // MFMA C/D frag

#define N 1024
#define NSQ (1024 * 1024)
#define NITER 30

__device__ __forceinline__ float b2f(u16 u) {
  union { unsigned int i; float f; } v;
  v.i = ((unsigned int)u) << 16;
  return v.f;
}

__device__ __forceinline__ u16 f2b(float f) {
  union { float f; unsigned int i; } v;
  v.f = f;
  return (u16)((v.i + 0x7fffu + ((v.i >> 16) & 1u)) >> 16);
}

// ---- input dtype detection -------------------------------------------------
__global__ void k_flag(const u16* a, float* flag) {
  if (threadIdx.x == 0 && blockIdx.x == 0) {
    int cnt = 0;
    for (int i = 0; i < 256; ++i) {
      const u16 u = a[2 * i];
      const int e = (u >> 7) & 0xFF;
      if (e >= 100 && e <= 132) ++cnt;
    }
    *flag = (cnt >= 128) ? 1.0f : 0.0f;
  }
}

__global__ void k_sentinel(void* out, const float* flag) {
  if (threadIdx.x == 0 && blockIdx.x == 0) {
    if (*flag > 0.5f) ((u16*)out)[0] = f2b(1000.0f);
    else              ((float*)out)[0] = 1000.0f;
  }
}

__global__ void k_cvt2(const void* a, float* o, const float* flag, int n) {
  const int i = blockIdx.x * 256 + threadIdx.x;
  if (i < n) {
    if (*flag > 0.5f) o[i] = b2f(((const u16*)a)[i]);
    else              o[i] = ((const float*)a)[i];
  }
}

// ---- fp32 -> bf16 (hi, lo) split helpers -----------------------------------
__global__ void k_split(const float* x, u16* h, u16* l) {
  const int i = blockIdx.x * 256 + threadIdx.x;
  const float v = x[i];
  const u16 hi = f2b(v);
  h[i] = hi;
  l[i] = f2b(v - b2f(hi));
}

// T = A^T, split to bf16 hi/lo.  grid (32,32), block (32,8)
__global__ void k_tsplit(const float* A, u16* Th, u16* Tl) {
  __shared__ float s[32][33];
  const int bx = blockIdx.x, by = blockIdx.y;
  const int tx = threadIdx.x, ty = threadIdx.y;
  for (int p = 0; p < 4; ++p)
    s[ty + p * 8][tx] = A[(by * 32 + ty + p * 8) * N + bx * 32 + tx];
  __syncthreads();
  for (int p = 0; p < 4; ++p) {
    const int rT = bx * 32 + ty + p * 8;
    const int cT = by * 32 + tx;
    const float v = s[tx][ty + p * 8];   // = A[cT][rT]
    const u16 hi = f2b(v);
    Th[rT * N + cT] = hi;
    Tl[rT * N + cT] = f2b(v - b2f(hi));
  }
}

__global__ void k_fillsplit(u16* h, u16* l, float v) {
  const int i = blockIdx.x * 256 + threadIdx.x;
  const u16 hi = f2b(v);
  h[i] = hi;
  l[i] = f2b(v - b2f(hi));
}

// ---- split-fp32 NT GEMM via bf16 MFMA --------------------------------------
// C[m][n] = sum_p sum_k P_p[m][k] * Q_p[n][k]   (C = sum_p P_p * Q_p^T)
// hi*hi + hi*lo + lo*hi with fp32 MFMA accumulation (~2^-17 rel error).
struct NTJob {
  const u16* ph[2]; const u16* pl[2];
  const u16* qh[2]; const u16* ql[2];
  float* c; u16* ch; u16* cl;
  int npairs; int wantc; int wantsplit;
};
struct NTBatch { NTJob j[4]; };

#define GLDS(g, l) __builtin_amdgcn_global_load_lds(                         \
    (const __attribute__((address_space(1))) void*)(g),                      \
    (__attribute__((address_space(3))) void*)(l), 16, 0, 0)

// 128x128 tile, BK=64, 4 waves as 2x2 (per-wave 64x64), double-buffered
// 128 KB LDS, grid (8,8,z) = 1 block/CU. Pipeline: counted vmcnt (T4) --
// next step's 16 GLDS/wave issued BEFORE the wait; s_waitcnt vmcnt(16)
// waits only for the current buffer's loads, so prefetch stays in flight
// across the raw s_barrier (no __syncthreads full drain). Every barrier is
// bracketed by asm memory clobbers so no LDS/GLDS op can cross it. XCD
// swizzle (T1, bijective: nwg%8==0 for all launches) gives each XCD a
// contiguous block chunk sharing A/B panels -> staging hits local L2.
// LDS [row][64] u16: row = 128 B = one bank wrap; 16B chunks XOR-swizzled
// (chunk ^= row&7) on both the pre-swizzled global source (linear GLDS
// dest) and the ds_read_b128 index -> conflict-free.
__global__ __launch_bounds__(256) void k_nt(NTBatch batch) {
  __shared__ u16 lds[2][4][128 * 64];   // [buf][Ph,Pl,Qh,Ql][row*64+k]

  const int tid = threadIdx.x;
  const int w = tid >> 6, lane = tid & 63;

  const int nwg = 64 * gridDim.z;
  const int d = blockIdx.x + 8 * blockIdx.y + 64 * blockIdx.z;
  const int lin = (d & 7) * (nwg >> 3) + (d >> 3);   // XCD-chunked, bijective
  const int bz = lin >> 6, by = (lin >> 3) & 7, bx = lin & 7;

  const NTJob job = batch.j[bz];
  const int m0 = by * 128, n0 = bx * 128;

  // staging: wave w stages matrix w (0:Ph 1:Pl 2:Qh 3:Ql).
  // GLDS j fills rows 8j..8j+7 linearly: lane q -> row 8j+(q>>3), dest chunk
  // q&7. Source chunk = destchunk ^ (row&7) = (q&7)^(q>>3).
  const int lrow = lane >> 3;
  const int lchk = (lane & 7) ^ lrow;
  const long lane_off = (long)((w < 2 ? m0 : n0) + lrow) * 2048 + (long)lchk * 16;
  const u16* src0 = (w == 0) ? job.ph[0] : (w == 1) ? job.pl[0]
                  : (w == 2) ? job.qh[0] : job.ql[0];
  const u16* src1 = (w == 0) ? job.ph[1] : (w == 1) ? job.pl[1]
                  : (w == 2) ? job.qh[1] : job.ql[1];

  // fragment read indices (u16 units): chunk = (kh*4+g) ^ (row&7);
  // kh=1 flips bit 5 of the u16 index (idx ^ 32).
  const int r0 = lane & 15, g = lane >> 4;
  const int wm = (w & 1) * 64, wn = (w >> 1) * 64;
  int idxA[4], idxB[4];
#pragma unroll
  for (int i = 0; i < 4; ++i) {
    int row = wm + i * 16 + r0;
    idxA[i] = row * 64 + ((g ^ (row & 7)) << 3);
    row = wn + i * 16 + r0;
    idxB[i] = row * 64 + ((g ^ (row & 7)) << 3);
  }

  f32x4 acc[4][4];
#pragma unroll
  for (int mt = 0; mt < 4; ++mt)
#pragma unroll
    for (int nt = 0; nt < 4; ++nt)
      acc[mt][nt] = (f32x4){0.0f, 0.0f, 0.0f, 0.0f};

  const int nsteps = job.npairs * 16;

  auto issue = [&](int s, int p) {
    const char* src = (const char*)((s & 16) ? src1 : src0) + lane_off
                    + (long)(s & 15) * 128;
    u16* dst = &lds[p][w][0];
#pragma unroll
    for (int j = 0; j < 16; ++j)
      GLDS(src + (long)j * 16384, dst + j * 512);
  };

  issue(0, 0);
  for (int s = 0; s < nsteps; ++s) {
    const int p = s & 1;
    if (s + 1 < nsteps) {
      issue(s + 1, p ^ 1);                              // 16 GLDS in flight
      asm volatile("s_waitcnt vmcnt(16)" ::: "memory"); // buf p landed
    } else {
      asm volatile("s_waitcnt vmcnt(0)" ::: "memory");
    }
    __builtin_amdgcn_s_barrier();
    asm volatile("" ::: "memory");
    const u16* Ahf = &lds[p][0][0];
    const u16* Alf = &lds[p][1][0];
    const u16* Bhf = &lds[p][2][0];
    const u16* Blf = &lds[p][3][0];
#pragma unroll
    for (int kh = 0; kh < 2; ++kh) {
      const int kx = kh * 32;
      short8 ah[4], al[4];
#pragma unroll
      for (int mt = 0; mt < 4; ++mt) {
        ah[mt] = *(const short8*)(Ahf + (idxA[mt] ^ kx));
        al[mt] = *(const short8*)(Alf + (idxA[mt] ^ kx));
      }
#pragma unroll
      for (int nt = 0; nt < 4; ++nt) {
        const short8 bh = *(const short8*)(Bhf + (idxB[nt] ^ kx));
        const short8 bl = *(const short8*)(Blf + (idxB[nt] ^ kx));
#pragma unroll
        for (int mt = 0; mt < 4; ++mt) {
          acc[mt][nt] = __builtin_amdgcn_mfma_f32_16x16x32_bf16(ah[mt], bh, acc[mt][nt], 0, 0, 0);
          acc[mt][nt] = __builtin_amdgcn_mfma_f32_16x16x32_bf16(ah[mt], bl, acc[mt][nt], 0, 0, 0);
          acc[mt][nt] = __builtin_amdgcn_mfma_f32_16x16x32_bf16(al[mt], bh, acc[mt][nt], 0, 0, 0);
        }
      }
    }
    asm volatile("" ::: "memory");
    __builtin_amdgcn_s_barrier();   // all waves done reading buf p
  }

  // C/D layout (m89-verified): col = lane&15, row = (lane>>4)*4 + reg
#pragma unroll
  for (int mt = 0; mt < 4; ++mt) {
    const int crow = m0 + wm + mt * 16 + g * 4;
#pragma unroll
    for (int nt = 0; nt < 4; ++nt) {
      const int ccol = n0 + wn + nt * 16 + r0;
#pragma unroll
      for (int jj = 0; jj < 4; ++jj) {
        const float v = acc[mt][nt][jj];
        const int o = (crow + jj) * N + ccol;
        if (job.wantc) job.c[o] = v;
        if (job.wantsplit) {
          const u16 hi = f2b(v);
          job.ch[o] = hi;
          job.cl[o] = f2b(v - b2f(hi));
        }
      }
    }
  }
}

// f = P0 + P1; optionally split f into bf16 hi/lo
__global__ void k_combine(const float* P0, const float* P1, float* f, u16* h, u16* l) {
  const int i = blockIdx.x * 256 + threadIdx.x;
  const float v = P0[i] + P1[i];
  f[i] = v;
  if (h) {
    const u16 hi = f2b(v);
    h[i] = hi;
    l[i] = f2b(v - b2f(hi));
  }
}

// ---- reductions -------------------------------------------------------------
__global__ void k_rsum(const float* x, float* slot) {
  __shared__ float red[256];
  const int tid = threadIdx.x;
  float a = 0.0f;
  for (int i = blockIdx.x * 256 + tid; i < NSQ; i += gridDim.x * 256)
    a += x[i] * x[i];
  red[tid] = a;
  __syncthreads();
  for (int off = 128; off > 0; off >>= 1) {
    if (tid < off) red[tid] += red[tid + off];
    __syncthreads();
  }
  if (tid == 0) atomicAdd(slot, red[0]);
}

__global__ void k_dot(const float* x, const float* y, float* slot) {
  __shared__ float red[256];
  const int tid = threadIdx.x;
  float a = 0.0f;
  for (int i = blockIdx.x * 256 + tid; i < NSQ; i += gridDim.x * 256)
    a += x[i] * y[i];
  red[tid] = a;
  __syncthreads();
  for (int off = 128; off > 0; off >>= 1) {
    if (tid < off) red[tid] += red[tid + off];
    __syncthreads();
  }
  if (tid == 0) atomicAdd(slot, red[0]);
}

// all 16 <U_ab, L_cd> dots in one pass
__global__ void k_dot16(const float* U0, const float* U1, const float* U2, const float* U3,
                        const float* L0, const float* L1, const float* L2, const float* L3,
                        float* slots) {
  __shared__ float red[256];
  const int tid = threadIdx.x;
  float a[16];
#pragma unroll
  for (int u = 0; u < 16; ++u) a[u] = 0.0f;
  for (int i = blockIdx.x * 256 + tid; i < NSQ; i += gridDim.x * 256) {
    const float u0 = U0[i], u1 = U1[i], u2 = U2[i], u3 = U3[i];
    const float l0 = L0[i], l1 = L1[i], l2 = L2[i], l3 = L3[i];
    a[0]  += u0 * l0; a[1]  += u0 * l1; a[2]  += u0 * l2; a[3]  += u0 * l3;
    a[4]  += u1 * l0; a[5]  += u1 * l1; a[6]  += u1 * l2; a[7]  += u1 * l3;
    a[8]  += u2 * l0; a[9]  += u2 * l1; a[10] += u2 * l2; a[11] += u2 * l3;
    a[12] += u3 * l0; a[13] += u3 * l1; a[14] += u3 * l2; a[15] += u3 * l3;
  }
  for (int u = 0; u < 16; ++u) {
    red[tid] = a[u];
    __syncthreads();
    for (int off = 128; off > 0; off >>= 1) {
      if (tid < off) red[tid] += red[tid + off];
      __syncthreads();
    }
    if (tid == 0) atomicAdd(slots + 402 + u, red[0]);
    __syncthreads();
  }
}

__global__ void k_zero(float* p) {
  const int i = blockIdx.x * 256 + threadIdx.x;
  p[i] = 0.0f;
}

// Finalize. Unnormalized iterates: eig = <r,Tr>/<r,r>, E0 = sum h*dots/(lr*eig^2).
__global__ void GMPOmodel_6794638262737_kernel(const void* h, const float* slots,
                                               void* out) {
  if (threadIdx.x == 0 && blockIdx.x == 0) {
    const float bf = slots[512];
    const float rr = slots[399];
    const float rw = slots[400];
    const float lr = slots[401];
    const float eig = rw / rr;
    float num = 0.0f;
    for (int u = 0; u < 16; ++u) {
      const float hv = (bf > 0.5f) ? b2f(((const u16*)h)[u]) : ((const float*)h)[u];
      num += hv * slots[402 + u];
    }
    const float e0 = num / (lr * eig * eig);
    if (bf > 0.5f) ((u16*)out)[0] = f2b(e0);
    else           ((float*)out)[0] = e0;
  }
}

// ---- host -------------------------------------------------------------------
static inline NTJob mkjob(const u16* ph0, const u16* pl0, const u16* qh0, const u16* ql0,
                          const u16* ph1, const u16* pl1, const u16* qh1, const u16* ql1,
                          float* c, u16* ch, u16* cl, int npairs, int wantc, int wantsplit) {
  NTJob j;
  j.ph[0] = ph0; j.pl[0] = pl0; j.qh[0] = qh0; j.ql[0] = ql0;
  j.ph[1] = ph1; j.pl[1] = pl1; j.qh[1] = qh1; j.ql[1] = ql1;
  j.c = c; j.ch = ch; j.cl = cl;
  j.npairs = npairs; j.wantc = wantc; j.wantsplit = wantsplit;
  return j;
}

extern "C" void kernel_launch(void* const* d_in, const int* in_sizes, int n_in,
                              void* d_out, int out_size, void* d_ws, size_t ws_size,
                              hipStream_t stream) {
  (void)in_sizes; (void)n_in; (void)out_size; (void)ws_size;
  const void* Ain = d_in[0];
  const void* hin = d_in[1];
  char* ws = (char*)d_ws;
  const size_t MB = 1u << 20;

  // Workspace is packed into 80 MB + 16 KB -- the footprint rounds 1-2 proved
  // safe. (Round 3 extended to 97 MB and the container died; suspected
  // workspace overflow -> OOB stores.) K-split partials alias fp32 buffers
  // that are dead during the loop; stream order makes every alias
  // read-before-overwrite.
  // bf16 split buffers (2 MB each)
  u16* A0h = (u16*)(ws + 0 * MB);   u16* A0l = (u16*)(ws + 2 * MB);
  u16* A1h = (u16*)(ws + 4 * MB);   u16* A1l = (u16*)(ws + 6 * MB);
  u16* T0h = (u16*)(ws + 8 * MB);   u16* T0l = (u16*)(ws + 10 * MB);
  u16* T1h = (u16*)(ws + 12 * MB);  u16* T1l = (u16*)(ws + 14 * MB);
  u16* rh  = (u16*)(ws + 16 * MB);  u16* rl  = (u16*)(ws + 18 * MB);
  u16* lh  = (u16*)(ws + 20 * MB);  u16* ll  = (u16*)(ws + 22 * MB);
  u16* t0rh = (u16*)(ws + 24 * MB); u16* t0rl = (u16*)(ws + 26 * MB);
  u16* t1rh = (u16*)(ws + 28 * MB); u16* t1rl = (u16*)(ws + 30 * MB);
  u16* t0lh = (u16*)(ws + 32 * MB); u16* t0ll = (u16*)(ws + 34 * MB);
  u16* t1lh = (u16*)(ws + 36 * MB); u16* t1ll = (u16*)(ws + 38 * MB);
  // fp32 buffers (4 MB each)
  float* A0f = (float*)(ws + 40 * MB);   // setup fp32 A0 -> loop P0 -> epi L00
  float* A1f = (float*)(ws + 44 * MB);   // setup fp32 A1 -> loop P1 -> epi L01
  float* rf  = (float*)(ws + 48 * MB);
  float* lf  = (float*)(ws + 52 * MB);
  float* wf  = (float*)(ws + 56 * MB);   // loop P2 -> epi mv_r(r) -> epi U00
  float* L10 = (float*)(ws + 60 * MB);   // loop P3 -> epi L10
  float* L11 = (float*)(ws + 64 * MB);
  float* U01 = (float*)(ws + 68 * MB);
  float* U10 = (float*)(ws + 72 * MB);
  float* U11 = (float*)(ws + 76 * MB);
  float* P0 = A0f, *P1 = A1f, *P2 = wf, *P3 = L10;  // K-split partials (loop)
  float* slots = (float*)(ws + 80 * MB); // 4096 floats; [512] = dtype flag

  k_zero<<<4, 256, 0, stream>>>(slots);
  k_flag<<<1, 64, 0, stream>>>((const u16*)Ain, slots + 512);
  k_sentinel<<<1, 64, 0, stream>>>(d_out, slots + 512);
  k_cvt2<<<8192, 256, 0, stream>>>(Ain, A0f, slots + 512, 2 * NSQ);  // fills A0f, A1f

  k_split<<<4096, 256, 0, stream>>>(A0f, A0h, A0l);
  k_split<<<4096, 256, 0, stream>>>(A1f, A1h, A1l);
  k_tsplit<<<dim3(32, 32), dim3(32, 8), 0, stream>>>(A0f, T0h, T0l);
  k_tsplit<<<dim3(32, 32), dim3(32, 8), 0, stream>>>(A1f, T1h, T1l);
  k_fillsplit<<<4096, 256, 0, stream>>>(rh, rl, 1.0f / 1024.0f);
  k_fillsplit<<<4096, 256, 0, stream>>>(lh, ll, 1.0f / 1024.0f);

  // r, l stay symmetric -> all GEMMs in NT form.
  // Stage 1 (z=4): t0r=A0*r, t1r=A1*r, t0l=A0^T*l, t1l=A1^T*l
  NTBatch s1;
  s1.j[0] = mkjob(A0h, A0l, rh, rl, 0, 0, 0, 0, 0, t0rh, t0rl, 1, 0, 1);
  s1.j[1] = mkjob(A1h, A1l, rh, rl, 0, 0, 0, 0, 0, t1rh, t1rl, 1, 0, 1);
  s1.j[2] = mkjob(T0h, T0l, lh, ll, 0, 0, 0, 0, 0, t0lh, t0ll, 1, 0, 1);
  s1.j[3] = mkjob(T1h, T1l, lh, ll, 0, 0, 0, 0, 0, t1lh, t1ll, 1, 0, 1);
  // Stage 2 K-split (z=4): partials of r' and l', combined afterwards.
  NTBatch s2;
  s2.j[0] = mkjob(t0rh, t0rl, A0h, A0l, 0, 0, 0, 0, P0, 0, 0, 1, 1, 0);
  s2.j[1] = mkjob(t1rh, t1rl, A1h, A1l, 0, 0, 0, 0, P1, 0, 0, 1, 1, 0);
  s2.j[2] = mkjob(t0lh, t0ll, T0h, T0l, 0, 0, 0, 0, P2, 0, 0, 1, 1, 0);
  s2.j[3] = mkjob(t1lh, t1ll, T1h, T1l, 0, 0, 0, 0, P3, 0, 0, 1, 1, 0);

  for (int it = 0; it < NITER; ++it) {
    k_nt<<<dim3(8, 8, 4), 256, 0, stream>>>(s1);
    k_nt<<<dim3(8, 8, 4), 256, 0, stream>>>(s2);
    k_combine<<<4096, 256, 0, stream>>>(P0, P1, rf, rh, rl);
    k_combine<<<4096, 256, 0, stream>>>(P2, P3, lf, lh, ll);
  }

  // ---- epilogue (unnormalized; E0 homogeneous deg 0 in r and l) ----
  // w = mv_r(r_final): recompute t from final r, K-split reduce, combine.
  NTBatch e1;
  e1.j[0] = mkjob(A0h, A0l, rh, rl, 0, 0, 0, 0, 0, t0rh, t0rl, 1, 0, 1);
  e1.j[1] = mkjob(A1h, A1l, rh, rl, 0, 0, 0, 0, 0, t1rh, t1rl, 1, 0, 1);
  k_nt<<<dim3(8, 8, 2), 256, 0, stream>>>(e1);
  NTBatch e2;
  e2.j[0] = mkjob(t0rh, t0rl, A0h, A0l, 0, 0, 0, 0, P0, 0, 0, 1, 1, 0);
  e2.j[1] = mkjob(t1rh, t1rl, A1h, A1l, 0, 0, 0, 0, P1, 0, 0, 1, 1, 0);
  k_nt<<<dim3(8, 8, 2), 256, 0, stream>>>(e2);
  k_combine<<<4096, 256, 0, stream>>>(P0, P1, wf, 0, 0);   // wf aliases P2 (ok)
  k_rsum<<<256, 256, 0, stream>>>(rf, slots + 399);          // rr
  k_dot<<<256, 256, 0, stream>>>(rf, wf, slots + 400);       // rw
  k_dot<<<256, 256, 0, stream>>>(lf, rf, slots + 401);       // lr

  // UL_a = l*A_a = NT(l, ATa); URT_b = (A_b r)^T = r*A_b^T = NT(r, A_b)
  NTBatch e3;
  e3.j[0] = mkjob(lh, ll, T0h, T0l, 0, 0, 0, 0, 0, t0lh, t0ll, 1, 0, 1);  // UL0
  e3.j[1] = mkjob(lh, ll, T1h, T1l, 0, 0, 0, 0, 0, t1lh, t1ll, 1, 0, 1);  // UL1
  e3.j[2] = mkjob(rh, rl, A0h, A0l, 0, 0, 0, 0, 0, t0rh, t0rl, 1, 0, 1);  // URT0
  e3.j[3] = mkjob(rh, rl, A1h, A1l, 0, 0, 0, 0, 0, t1rh, t1rl, 1, 0, 1);  // URT1
  k_nt<<<dim3(8, 8, 4), 256, 0, stream>>>(e3);

  // L_cd = A_c*A_d = NT(A_c, ATd); fp32 only. A0f/A1f consumed -> L00/L01.
  NTBatch e4;
  e4.j[0] = mkjob(A0h, A0l, T0h, T0l, 0, 0, 0, 0, A0f, 0, 0, 1, 1, 0);
  e4.j[1] = mkjob(A0h, A0l, T1h, T1l, 0, 0, 0, 0, A1f, 0, 0, 1, 1, 0);
  e4.j[2] = mkjob(A1h, A1l, T0h, T0l, 0, 0, 0, 0, L10, 0, 0, 1, 1, 0);
  e4.j[3] = mkjob(A1h, A1l, T1h, T1l, 0, 0, 0, 0, L11, 0, 0, 1, 1, 0);
  k_nt<<<dim3(8, 8, 4), 256, 0, stream>>>(e4);

  // U_ab = UL_a * UR_b = NT(UL_a, URT_b); wf dead after rw dot -> U00.
  NTBatch e5;
  e5.j[0] = mkjob(t0lh, t0ll, t0rh, t0rl, 0, 0, 0, 0, wf,  0, 0, 1, 1, 0);
  e5.j[1] = mkjob(t0lh, t0ll, t1rh, t1rl, 0, 0, 0, 0, U01, 0, 0, 1, 1, 0);
  e5.j[2] = mkjob(t1lh, t1ll, t0rh, t0rl, 0, 0, 0, 0, U10, 0, 0, 1, 1, 0);
  e5.j[3] = mkjob(t1lh, t1ll, t1rh, t1rl, 0, 0, 0, 0, U11, 0, 0, 1, 1, 0);
  k_nt<<<dim3(8, 8, 4), 256, 0, stream>>>(e5);

  k_dot16<<<256, 256, 0, stream>>>(wf, U01, U10, U11, A0f, A1f, L10, L11, slots);

  GMPOmodel_6794638262737_kernel<<<1, 64, 0, stream>>>(hin, slots, d_out);
}